// Round 4
// baseline (677.659 us; speedup 1.0000x reference)
//
#include <hip/hip_runtime.h>
#include <hip/hip_bf16.h>

// ---- problem constants ----
#define BATCH 4
#define SEQ   2048
#define DIN   4096
#define DOUT  4096
#define MTOT  (BATCH * SEQ)     // 8192
#define RANK  16

typedef __bf16 bf8_t  __attribute__((ext_vector_type(8)));
typedef float  f4_t   __attribute__((ext_vector_type(4)));

#define GLD_LDS(g, l) \
  __builtin_amdgcn_global_load_lds((const __attribute__((address_space(1))) void*)(g), \
                                   (__attribute__((address_space(3))) void*)(l), 16, 0, 0)

// ---------------------------------------------------------------------------
// Kernel A: streaming f32 -> bf16 conversion, fully coalesced, 8 elem/thread.
// Used for both W (8192 blocks) and x (16384 blocks).
// ---------------------------------------------------------------------------
__global__ __launch_bounds__(256) void conv_kernel(
    const float* __restrict__ src, __bf16* __restrict__ dst) {
  const size_t i = ((size_t)blockIdx.x * 256 + threadIdx.x) * 8;
  f4_t a = *(const f4_t*)(src + i);
  f4_t b = *(const f4_t*)(src + i + 4);
  bf8_t o;
#pragma unroll
  for (int e = 0; e < 4; ++e) { o[e] = (__bf16)a[e]; o[4 + e] = (__bf16)b[e]; }
  *(bf8_t*)(dst + i) = o;
}

// ---------------------------------------------------------------------------
// Kernel B: lowS[m][r] += scale * sum_k xb[m][k]*A[b][r][k]  (MFMA, k-split=8)
// Reads pre-converted bf16 xb (L2/L3-warm, 16B/lane direct A-frag loads, no
// cvt VALU for x). A rows (f32, 256KB/adapter) cvt in-register, L2-resident.
// Block = 256 thr = 4 waves; wave owns 16 rows x 512 k. grid = (128, 8).
// lowS zeroed before launch (hipMemsetAsync).
// ---------------------------------------------------------------------------
__global__ __launch_bounds__(256) void lora_low_kernel(
    const __bf16* __restrict__ xb, const float* __restrict__ Aw,
    const float* __restrict__ scales, const int* __restrict__ adapter_id,
    float* __restrict__ lowS) {
  const int t    = threadIdx.x;
  const int w    = t >> 6;
  const int lane = t & 63;
  const int quad = lane >> 4;
  const int l16  = lane & 15;
  const int m0   = blockIdx.x * 64;
  const int kb   = blockIdx.y * 512;
  const int b    = adapter_id[m0 >> 11];
  const float scale = scales[b];

  const int row = m0 + w * 16 + l16;
  const __bf16* xp = xb + (size_t)row * DIN + kb + quad * 8;
  const float*  ap = Aw + ((size_t)b * RANK + l16) * DIN + kb + quad * 8;

  f4_t acc = (f4_t)0.f;
#pragma unroll 4
  for (int it = 0; it < 16; ++it) {
    const int off = it * 32;
    bf8_t af = *(const bf8_t*)(xp + off);
    f4_t v0 = *(const f4_t*)(ap + off);
    f4_t v1 = *(const f4_t*)(ap + off + 4);
    bf8_t bfr;
#pragma unroll
    for (int e = 0; e < 4; ++e) { bfr[e] = (__bf16)v0[e]; bfr[4 + e] = (__bf16)v1[e]; }
    acc = __builtin_amdgcn_mfma_f32_16x16x32_bf16(af, bfr, acc, 0, 0, 0);
  }

  // C/D: col(rank) = l16, row = quad*4 + e.  Partial over k-split -> atomicAdd.
#pragma unroll
  for (int e = 0; e < 4; ++e)
    atomicAdd(&lowS[(size_t)(m0 + w * 16 + quad * 4 + e) * RANK + l16], acc[e] * scale);
}

// ---------------------------------------------------------------------------
// Kernel C: out = x @ W^T + bias + lowS @ loraB[b]^T   (bf16 GEMM, f32 out)
// m97 structure: 128x128 tile, BK=32 bf16, global_load_lds width-16, 4 waves
// x 4x4 subtiles of 16x16x32 MFMA. (Byte-identical to R3 — pre-pass A/B.)
// ---------------------------------------------------------------------------
#define TM 128
#define TN 128
#define BK 32

__global__ __launch_bounds__(256) void lora_gemm_kernel(
    const __bf16* __restrict__ x, const __bf16* __restrict__ wgt,
    const float* __restrict__ bias, const float* __restrict__ loraB,
    const int* __restrict__ adapter_id, const float* __restrict__ lowS,
    float* __restrict__ out) {
  __shared__ __bf16 As[TM * BK];   // 8 KB
  __shared__ __bf16 Bs[TN * BK];   // 8 KB

  const int t    = threadIdx.x;
  const int w    = t >> 6;
  const int lane = t & 63;
  const int quad = lane >> 4;
  const int l16  = lane & 15;
  const int m0 = blockIdx.y * TM;
  const int n0 = blockIdx.x * TN;
  const int wave_m = (w & 1) * 64;
  const int wave_n = (w >> 1) * 64;

  f4_t acc[4][4];
#pragma unroll
  for (int i = 0; i < 4; ++i)
#pragma unroll
    for (int j = 0; j < 4; ++j) acc[i][j] = (f4_t)0.f;

  // staging: round r covers rows r*64 + (t>>2); chunk-position (t&3) of row rr
  // holds global chunk (t&3)^(rr&3)  (8 bf16 = 16 B chunks, 4 per row)
  const int srow   = t >> 2;                    // 0..63
  const int schunk = (t & 3) ^ (srow & 3);      // XOR swizzle
  const __bf16* gA0 = x   + (size_t)(m0 + srow) * DIN + schunk * 8;
  const __bf16* gA1 = x   + (size_t)(m0 + 64 + srow) * DIN + schunk * 8;
  const __bf16* gB0 = wgt + (size_t)(n0 + srow) * DIN + schunk * 8;
  const __bf16* gB1 = wgt + (size_t)(n0 + 64 + srow) * DIN + schunk * 8;
  __bf16* lA0 = &As[w * 512];          // wave-uniform LDS bases (+lane*16B in HW)
  __bf16* lA1 = &As[2048 + w * 512];
  __bf16* lB0 = &Bs[w * 512];
  __bf16* lB1 = &Bs[2048 + w * 512];

  // frag-read chunk (per-thread constant): want global chunk `quad` at rows
  // with row&3 == l16&3  ->  LDS chunk = quad ^ (l16&3)
  const int fc = (quad ^ (l16 & 3)) * 8;

  for (int k0 = 0; k0 < DIN; k0 += BK) {
    GLD_LDS(gA0 + k0, lA0);
    GLD_LDS(gA1 + k0, lA1);
    GLD_LDS(gB0 + k0, lB0);
    GLD_LDS(gB1 + k0, lB1);
    __syncthreads();   // drains vmcnt -> staged data visible

    bf8_t af[4], bfr[4];
#pragma unroll
    for (int i = 0; i < 4; ++i)
      af[i] = *(const bf8_t*)&As[(wave_m + i * 16 + l16) * BK + fc];
#pragma unroll
    for (int j = 0; j < 4; ++j)
      bfr[j] = *(const bf8_t*)&Bs[(wave_n + j * 16 + l16) * BK + fc];
#pragma unroll
    for (int i = 0; i < 4; ++i)
#pragma unroll
      for (int j = 0; j < 4; ++j)
        acc[i][j] = __builtin_amdgcn_mfma_f32_16x16x32_bf16(af[i], bfr[j], acc[i][j], 0, 0, 0);

    __syncthreads();   // protect LDS from next iteration's staging
  }

  // ---- LoRA epilogue: one zero-padded MFMA k-step (k=0..15 valid) ----
  const int b = adapter_id[m0 >> 11];
  bf8_t alow[4], blow[4];
  if (quad < 2) {
#pragma unroll
    for (int i = 0; i < 4; ++i) {
      const float* p = &lowS[(size_t)(m0 + wave_m + i * 16 + l16) * RANK + quad * 8];
      f4_t u0 = *(const f4_t*)p;
      f4_t u1 = *(const f4_t*)(p + 4);
#pragma unroll
      for (int e = 0; e < 4; ++e) { alow[i][e] = (__bf16)u0[e]; alow[i][4 + e] = (__bf16)u1[e]; }
    }
#pragma unroll
    for (int j = 0; j < 4; ++j) {
      const float* p = &loraB[((size_t)b * DOUT + n0 + wave_n + j * 16 + l16) * RANK + quad * 8];
      f4_t u0 = *(const f4_t*)p;
      f4_t u1 = *(const f4_t*)(p + 4);
#pragma unroll
      for (int e = 0; e < 4; ++e) { blow[j][e] = (__bf16)u0[e]; blow[j][4 + e] = (__bf16)u1[e]; }
    }
  } else {
#pragma unroll
    for (int i = 0; i < 4; ++i)
#pragma unroll
      for (int e = 0; e < 8; ++e) { alow[i][e] = (__bf16)0.f; blow[i][e] = (__bf16)0.f; }
  }
#pragma unroll
  for (int i = 0; i < 4; ++i)
#pragma unroll
    for (int j = 0; j < 4; ++j)
      acc[i][j] = __builtin_amdgcn_mfma_f32_16x16x32_bf16(alow[i], blow[j], acc[i][j], 0, 0, 0);

  // ---- bias + store (C/D layout: col = lane&15, row = quad*4 + reg) ----
#pragma unroll
  for (int j = 0; j < 4; ++j) {
    const int c = n0 + wave_n + j * 16 + l16;
    const float bc = bias[c];
#pragma unroll
    for (int i = 0; i < 4; ++i) {
      const int r0 = m0 + wave_m + i * 16 + quad * 4;
#pragma unroll
      for (int e = 0; e < 4; ++e)
        out[(size_t)(r0 + e) * DOUT + c] = acc[i][j][e] + bc;
    }
  }
}

extern "C" void kernel_launch(void* const* d_in, const int* in_sizes, int n_in,
                              void* d_out, int out_size, void* d_ws, size_t ws_size,
                              hipStream_t stream) {
  const float* x       = (const float*)d_in[0];
  const float* weight  = (const float*)d_in[1];
  const float* bias    = (const float*)d_in[2];
  const float* lora_a  = (const float*)d_in[3];
  const float* lora_b  = (const float*)d_in[4];
  const float* scaling = (const float*)d_in[5];
  const int*   adapter = (const int*)d_in[6];
  float* out = (float*)d_out;

  // workspace layout: x_bf16 (64 MiB) | W_bf16 (32 MiB) | lowS (512 KiB)
  __bf16* xb   = (__bf16*)d_ws;
  __bf16* wb   = xb + (size_t)MTOT * DIN;
  float*  lowS = (float*)(wb + (size_t)DOUT * DIN);

  hipMemsetAsync(lowS, 0, (size_t)MTOT * RANK * sizeof(float), stream);
  conv_kernel<<<(size_t)MTOT * DIN / 8 / 256, 256, 0, stream>>>(x, xb);
  conv_kernel<<<(size_t)DOUT * DIN / 8 / 256, 256, 0, stream>>>(weight, wb);
  dim3 lgrid(MTOT / 64, 8);
  lora_low_kernel<<<lgrid, 256, 0, stream>>>(xb, lora_a, scaling, adapter, lowS);
  dim3 grid(DOUT / TN, MTOT / TM);
  lora_gemm_kernel<<<grid, 256, 0, stream>>>(xb, wb, bias, lora_b, adapter, lowS, out);
}